// Round 5
// baseline (613.998 us; speedup 1.0000x reference)
//
#include <hip/hip_runtime.h>
#include <hip/hip_bf16.h>

// ---------------------------------------------------------------------------
// Types / helpers
// ---------------------------------------------------------------------------
typedef __bf16 bf16x8 __attribute__((ext_vector_type(8)));
typedef float f32x16 __attribute__((ext_vector_type(16)));

// fp32 -> bf16 bits, round-to-nearest-even (inputs are finite; no NaN path)
__device__ __forceinline__ unsigned short f2bs(float f) {
    unsigned u = __builtin_bit_cast(unsigned, f);
    u = (u + 0x7fffu + ((u >> 16) & 1u)) >> 16;
    return (unsigned short)u;
}
__device__ __forceinline__ float bs2f(unsigned short s) {
    unsigned u = ((unsigned)s) << 16;
    return __builtin_bit_cast(float, u);
}

#define GLDS16(gp, lp)                                                        \
    __builtin_amdgcn_global_load_lds(                                         \
        (const __attribute__((address_space(1))) void*)(gp),                  \
        (__attribute__((address_space(3))) void*)(lp), 16, 0, 0)

#define TCHUNK 32

// ---------------------------------------------------------------------------
// Kernel 1a: per-chunk sums + write the h-half of X in bf16.
// ---------------------------------------------------------------------------
__global__ __launch_bounds__(256) void feats_partial(
    const float* __restrict__ h, float* __restrict__ partial,
    unsigned short* __restrict__ X, int B, int T, int D, int nC) {
    const int d = blockIdx.z * 256 + threadIdx.x;
    const int b = blockIdx.x, c = blockIdx.y;
    const int t0 = c * TCHUNK;
    const int t1 = min(t0 + TCHUNK, T);
    const float* hp = h + ((long)b * T + t0) * D + d;
    unsigned short* xp = X + ((long)b * T + t0) * (2 * D) + D + d;
    float s = 0.f;
    for (int t = t0; t < t1; ++t) {
        float v = *hp;
        *xp = f2bs(v);
        s += v;
        hp += D;
        xp += 2 * D;
    }
    partial[((long)b * nC + c) * D + d] = s;
}

// ---------------------------------------------------------------------------
// Kernel 1b: write the prefix-mean half.
// R14: running sum now read from h (fp32) instead of the bf16 X.h readback.
// The old xp[0]-store / xp[D]-load pair was a same-pointer dependence the
// compiler could not disambiguate -> serialized t-loop. h is a distinct
// restrict pointer -> loop pipelines. Also numerically closer to the
// reference (fp32 cumsum of fp32 values).
// ---------------------------------------------------------------------------
__global__ __launch_bounds__(256) void feats_write(
    const float* __restrict__ h, const float* __restrict__ partial,
    unsigned short* __restrict__ X, int B, int T, int D, int nC) {
    const int d = blockIdx.z * 256 + threadIdx.x;
    const int b = blockIdx.x, c = blockIdx.y;
    const int t0 = c * TCHUNK;
    const int t1 = min(t0 + TCHUNK, T);
    float sum = 0.f;
    for (int cc = 0; cc < c; ++cc)
        sum += partial[((long)b * nC + cc) * D + d];
    const float* hp = h + ((long)b * T + t0) * D + d;
    unsigned short* xp = X + ((long)b * T + t0) * (2 * D) + d;
    for (int t = t0; t < t1; ++t) {
        float pm = (t == 0) ? 0.f : sum / (float)t;
        xp[0] = f2bs(pm);
        sum += *hp;
        hp += D;
        xp += 2 * D;
    }
}

// ---------------------------------------------------------------------------
// Kernel 2: transpose + cast. W: [K][N] fp32 -> WT: [N][K] bf16 bits.
// ---------------------------------------------------------------------------
__global__ __launch_bounds__(256) void transpose_cast(
    const float* __restrict__ W, unsigned short* __restrict__ WT,
    int K, int N) {
    __shared__ float tile[32][33];
    const int n0 = blockIdx.x * 32, k0 = blockIdx.y * 32;
    const int tx = threadIdx.x, ty = threadIdx.y;
    #pragma unroll
    for (int i = ty; i < 32; i += 8)
        tile[i][tx] = W[(long)(k0 + i) * N + n0 + tx];
    __syncthreads();
    #pragma unroll
    for (int i = ty; i < 32; i += 8)
        WT[(long)(n0 + i) * K + k0 + tx] = f2bs(tile[tx][i]);
}

// ---------------------------------------------------------------------------
// Kernel 2b: out[m] = b3 (init for the fused-head atomics)
// ---------------------------------------------------------------------------
__global__ __launch_bounds__(256) void init_out(
    float* __restrict__ out, const float* __restrict__ b3, int M) {
    int m = blockIdx.x * 256 + threadIdx.x;
    if (m < M) out[m] = b3[0];
}

// ---------------------------------------------------------------------------
// Kernel 3: GEMM  C[M,N] = relu(A[M,K] * BT[N,K]^T + bias)
//
// R14: FRAGMENT-MAJOR LDS layout. R10-R13 lesson: SQ_LDS_BANK_CONFLICT was
// bit-identical (1.873e7 = 4.0 cy per ds_read_b128) under THREE different
// analytic XOR swizzles -> stop deriving swizzles; make reads linear by
// construction. Roofline recalc: strided-b128 achievable is 85 B/cy (m134),
// so per K-tile per CU: 192KB reads = 2259cy + 768cy conflict tax = 3027cy
// vs 2048cy MFMA floor -> kernel was LDS-READ-BOUND (util ceiling ~68%,
// measured 44%).
//
// Layout: lds[buf][A|B][kh][1024 chunks of 16B], chunk index =
//   A: ((wm*4 + m)*2 + kl)*64 + lane      (wm,m = wave-row/frag, kl = ks&1)
//   B: ((wn*2 + n)*2 + kl)*64 + lane
// Every frag read = base + lane*16B = 1024B CONTIGUOUS per wave (the
// canonical conflict-free pattern, same as the staging writes). The
// (row,k)<->(frag,lane) bijection reproduces the verified old fragment
// semantics exactly: lane holds row (lane&31), k = ks*16 + (lane>>5)*8.
// Staging: global_load_lds dest stays LINEAR (tid*16B); the per-lane GLOBAL
// source address is the permutation (rule 21 with identity LDS swizzle):
//   A unit u=kh: row = ((tid>>7)&3)*32 + (tid&31) [+128 for 2nd load],
//                kelem = kh*32 + ((tid>>6)&1)*16 + ((tid>>5)&1)*8
//   B unit: row = ((tid>>8)&1)*64 + ((tid>>7)&1)*32 + (tid&31) [+128]
// Global segments shrink 64B->32B per row; request count 2x, absorbed by
// L2/L3 (all bytes used across the K-loop).
//
// SCHEDULE: unchanged R11 best (3 barriers/K-tile, vmcnt(6) gate, setprio).
// R12 lesson: post-gate stage bursts regress; keep the R11 distribution.
// ASYMMETRIC READ: if conflicts do NOT vanish with fully-linear reads, the
// counter is gload_lds/ds_read pipe interference -> stop steering by it.
// REGISTER MODEL: 128 acc + ~104 arch -> 2 waves/SIMD. LESSONS kept: no
// min-waves launch_bounds (R4); <=128 acc (R8); C/D layout col=lane&31,
// row=(reg&3)+8*(reg>>2)+4*(lane>>5) (m74/m101); row-supertile XCD map.
// ---------------------------------------------------------------------------

#define PH_READS(c, ks, AF, BF)                                               \
    _Pragma("unroll")                                                         \
    for (int m_ = 0; m_ < 4; ++m_)                                            \
        AF[m_] = *(const bf16x8*)(&lds[c][0][(ks) >> 1][0] + baseA[m_] +      \
                                  ((ks) & 1) * 512);                          \
    _Pragma("unroll")                                                         \
    for (int n_ = 0; n_ < 2; ++n_)                                            \
        BF[n_] = *(const bf16x8*)(&lds[c][1][(ks) >> 1][0] + baseB[n_] +      \
                                  ((ks) & 1) * 512);

#define PH_MFMA(AF, BF)                                                       \
    __builtin_amdgcn_s_setprio(1);                                            \
    _Pragma("unroll")                                                         \
    for (int m_ = 0; m_ < 4; ++m_)                                            \
        _Pragma("unroll")                                                     \
        for (int n_ = 0; n_ < 2; ++n_)                                        \
            acc[m_][n_] = __builtin_amdgcn_mfma_f32_32x32x16_bf16(            \
                AF[m_], BF[n_], acc[m_][n_], 0, 0, 0);                        \
    __builtin_amdgcn_s_setprio(0);

#define PH(c, ks)                                                             \
    {                                                                         \
        bf16x8 af[4], bfr[2];                                                 \
        PH_READS(c, ks, af, bfr);                                             \
        PH_MFMA(af, bfr);                                                     \
    }

#define BAR()                                                                 \
    __builtin_amdgcn_sched_barrier(0);                                        \
    __builtin_amdgcn_s_barrier();                                             \
    __builtin_amdgcn_sched_barrier(0);

#define GROUP(c, o, t)                                                        \
  {                                                                           \
    /* stretch 1: stage next A-Kh1, gate on tile t, sync */                   \
    if ((t) + 1 < NT) stageA(o, 1, (t) + 1);                                  \
    if ((t) == NT - 1)                                                        \
        asm volatile("s_waitcnt vmcnt(0)" ::: "memory");                      \
    else                                                                      \
        asm volatile("s_waitcnt vmcnt(6)" ::: "memory");                      \
    BAR();                                                                    \
    /* stretch 2: ks0 + ks1 on Kh0; stage next B-Kh1 */                       \
    PH(c, 0);                                                                 \
    if ((t) + 1 < NT) stageB(o, 1, (t) + 1);                                  \
    PH(c, 1);                                                                 \
    BAR();                                                                    \
    /* stretch 3: ks2 + ks3 on Kh1; stage Kh0(t+2) into freed planes */       \
    if ((t) + 2 < NT) stageA(c, 0, (t) + 2);                                  \
    PH(c, 2);                                                                 \
    if ((t) + 2 < NT) stageB(c, 0, (t) + 2);                                  \
    PH(c, 3);                                                                 \
    BAR();                                                                    \
  }

template <bool FUSE>
__global__ __launch_bounds__(512) void gemm_bt_bias_relu(
    const unsigned short* __restrict__ A,   // [M,K] bf16 bits
    const unsigned short* __restrict__ BT,  // [N,K] bf16 bits
    const float* __restrict__ bias,         // [N]
    unsigned short* __restrict__ C,         // [M,N] bf16 bits (unused if FUSE)
    const float* __restrict__ W3,           // [N] head weights (FUSE only)
    float* __restrict__ outp,               // [M] (FUSE only)
    int M, int N, int K) {
    // [dbuf][A=0/B=1][kh][8192 elems = 1024 x 16B frag chunks] : 128 KiB
    __shared__ __align__(16) unsigned short lds[2][2][2][8192];

    const int tid = threadIdx.x;
    const int lane = tid & 63;
    const int wave = tid >> 6;
    const int wm = wave >> 2;   // 0..1 -> rows wm*128..+127
    const int wn = wave & 3;    // 0..3 -> cols wn*64..+63
    const int l31 = lane & 31;
    const int half = lane >> 5;

    // ---- m204 bijective XCD chunking over a row-supertile order ----
    const int nRow = M >> 8;            // 127
    const int nCol = N >> 8;            // 8 (GEMM1) / 4 (GEMM2)
    const int nwg = nRow * nCol;
    const int q = nwg >> 3, r = nwg & 7;
    const int x = blockIdx.x & 7;
    const int sidx = blockIdx.x >> 3;
    const int L = (x < r ? x * (q + 1) : r * (q + 1) + (x - r) * q) + sidx;
    // supertile = 8 row-blocks x nCol col-blocks
    const int perSup = 8 * nCol;
    const int nFull = nRow >> 3;        // 15
    const int fullL = nFull * perSup;
    int row_blk, col_blk;
    if (L < fullL) {
        const int sup = L / perSup;
        const int w = L - sup * perSup;
        row_blk = sup * 8 + (w & 7);
        col_blk = w >> 3;
    } else {
        const int rem = L - fullL;
        const int rt = nRow - nFull * 8;  // 7
        row_blk = nFull * 8 + rem % rt;
        col_blk = rem / rt;
    }
    const long row0 = (long)row_blk * 256;
    const long col0 = (long)col_blk * 256;

    // ---- frag-major staging source decode (per-lane global permutation) --
    // A chunk g = u*512 + tid (u = 0/1 -> +128 rows):
    //   lane=g&63, kl=(g>>6)&1, m=(g>>7)&3, wm=g>>9
    const int rowAs = ((tid >> 7) & 3) * 32 + (tid & 31);            // [0,128)
    const int rowBs = ((tid >> 8) & 1) * 64 + ((tid >> 7) & 1) * 32 +
                      (tid & 31);                                    // [0,128)
    const int kels = ((tid >> 6) & 1) * 16 + ((tid >> 5) & 1) * 8;   // elem col
    const unsigned short* Asrc = A + (row0 + rowAs) * K + kels;
    const unsigned short* Bsrc = BT + (col0 + rowBs) * K + kels;

    auto stageA = [&](int c, int kh, int kt) {
        GLDS16(Asrc + (long)kt * 64 + kh * 32, &lds[c][0][kh][tid * 8]);
        GLDS16(Asrc + (long)128 * K + (long)kt * 64 + kh * 32,
               &lds[c][0][kh][(512 + tid) * 8]);
    };
    auto stageB = [&](int c, int kh, int kt) {
        GLDS16(Bsrc + (long)kt * 64 + kh * 32, &lds[c][1][kh][tid * 8]);
        GLDS16(Bsrc + (long)128 * K + (long)kt * 64 + kh * 32,
               &lds[c][1][kh][(512 + tid) * 8]);
    };

    // ---- per-lane LDS read offsets (elements within a kh-plane) ----
    // A frag (m, ks): ((wm*4+m)*2 + (ks&1))*512 elems + lane*8
    int baseA[4], baseB[2];
    #pragma unroll
    for (int m = 0; m < 4; ++m)
        baseA[m] = (wm * 4 + m) * 1024 + lane * 8;
    #pragma unroll
    for (int n = 0; n < 2; ++n)
        baseB[n] = (wn * 2 + n) * 1024 + lane * 8;

    f32x16 acc[4][2];
    #pragma unroll
    for (int i = 0; i < 4; ++i)
        #pragma unroll
        for (int j = 0; j < 2; ++j)
            acc[i][j] = (f32x16)(0.f);

    const int NT = K >> 6;  // K-tiles of 64 (24 / 32 here; even)

    // ---- prologue: tile0 (4 units) + tile1 Kh0 (2 units), 12 loads ----
    stageA(0, 0, 0); stageB(0, 0, 0);
    stageA(0, 1, 0); stageB(0, 1, 0);
    stageA(1, 0, 1); stageB(1, 0, 1);

    for (int t = 0; t < NT; t += 2) {
        GROUP(0, 1, t);
        GROUP(1, 0, t + 1);
    }

    // Epilogue. C/D: col=lane&31, row=(reg&3)+8*(reg>>2)+4*half (m74/m101)
    if (!FUSE) {
        float bv[2];
        #pragma unroll
        for (int jt = 0; jt < 2; ++jt)
            bv[jt] = bias[col0 + wn * 64 + jt * 32 + l31];
        #pragma unroll
        for (int it = 0; it < 4; ++it) {
            #pragma unroll
            for (int reg = 0; reg < 16; ++reg) {
                const long row = row0 + wm * 128 + it * 32 + (reg & 3) +
                                 8 * (reg >> 2) + 4 * half;
                #pragma unroll
                for (int jt = 0; jt < 2; ++jt) {
                    const long col = col0 + wn * 64 + jt * 32 + l31;
                    float v = fmaxf(acc[it][jt][reg] + bv[jt], 0.f);
                    C[row * N + col] = f2bs(v);
                }
            }
        }
    } else {
        float w3v[2], bv[2];
        #pragma unroll
        for (int jt = 0; jt < 2; ++jt) {
            const long col = col0 + wn * 64 + jt * 32 + l31;
            w3v[jt] = W3[col];
            bv[jt] = bias[col];
        }
        #pragma unroll
        for (int it = 0; it < 4; ++it) {
            #pragma unroll
            for (int reg = 0; reg < 16; ++reg) {
                float s = 0.f;
                #pragma unroll
                for (int jt = 0; jt < 2; ++jt)
                    s += fmaxf(acc[it][jt][reg] + bv[jt], 0.f) * w3v[jt];
                s += __shfl_xor(s, 1, 64);
                s += __shfl_xor(s, 2, 64);
                s += __shfl_xor(s, 4, 64);
                s += __shfl_xor(s, 8, 64);
                s += __shfl_xor(s, 16, 64);
                if (l31 == 0) {
                    const long row = row0 + wm * 128 + it * 32 + (reg & 3) +
                                     8 * (reg >> 2) + 4 * half;
                    atomicAdd(&outp[row], s);
                }
            }
        }
    }
}

// ---------------------------------------------------------------------------
// Launch
// ---------------------------------------------------------------------------
extern "C" void kernel_launch(void* const* d_in, const int* in_sizes, int n_in,
                              void* d_out, int out_size, void* d_ws,
                              size_t ws_size, hipStream_t stream) {
    const float* h  = (const float*)d_in[0];
    const float* W1 = (const float*)d_in[1];
    const float* b1 = (const float*)d_in[2];
    const float* W2 = (const float*)d_in[3];
    const float* b2 = (const float*)d_in[4];
    const float* W3 = (const float*)d_in[5];
    const float* b3 = (const float*)d_in[6];
    float* out = (float*)d_out;

    const int B = 128, T = 254, D = 768, H = 1024;
    const int M = B * T;        // 32512 = 127 * 256
    const int K1 = 2 * D;       // 1536
    const int N1 = 2 * H;       // 2048
    const int K2 = N1;          // 2048
    const int N2 = H;           // 1024
    const int nC = (T + TCHUNK - 1) / TCHUNK;  // 8

    char* ws = (char*)d_ws;
    size_t off = 0;
    auto alloc = [&](size_t bytes) {
        char* p = ws + off;
        off += (bytes + 255) & ~(size_t)255;
        return p;
    };
    unsigned short* X   = (unsigned short*)alloc((size_t)M * K1 * 2);  // 99.9 MB
    unsigned short* H1  = (unsigned short*)alloc((size_t)M * N1 * 2);  // 133.2 MB
    unsigned short* W1T = (unsigned short*)alloc((size_t)N1 * K1 * 2); // 6.3 MB
    unsigned short* W2T = (unsigned short*)alloc((size_t)N2 * K2 * 2); // 4.2 MB
    float* partial      = (float*)alloc((size_t)B * nC * D * 4);       // 3.1 MB

    dim3 tb(32, 8);
    transpose_cast<<<dim3(N1 / 32, K1 / 32), tb, 0, stream>>>(W1, W1T, K1, N1);
    transpose_cast<<<dim3(N2 / 32, K2 / 32), tb, 0, stream>>>(W2, W2T, K2, N2);

    feats_partial<<<dim3(B, nC, D / 256), 256, 0, stream>>>(
        h, partial, X, B, T, D, nC);
    feats_write<<<dim3(B, nC, D / 256), 256, 0, stream>>>(
        h, partial, X, B, T, D, nC);

    init_out<<<dim3((M + 255) / 256), 256, 0, stream>>>(out, b3, M);

    // 256x256 tiles, 512 threads, 3-barrier K-tile schedule
    gemm_bt_bias_relu<false><<<dim3((M / 256) * (N1 / 256)), 512, 0, stream>>>(
        X, W1T, b1, H1, nullptr, nullptr, M, N1, K1);
    gemm_bt_bias_relu<true><<<dim3((M / 256) * (N2 / 256)), 512, 0, stream>>>(
        H1, W2T, b2, nullptr, W3, out, M, N2, K2);
}

// Round 6
// 578.883 us; speedup vs baseline: 1.0607x; 1.0607x over previous
//
#include <hip/hip_runtime.h>
#include <hip/hip_bf16.h>

// ---------------------------------------------------------------------------
// Types / helpers
// ---------------------------------------------------------------------------
typedef __bf16 bf16x8 __attribute__((ext_vector_type(8)));
typedef float f32x16 __attribute__((ext_vector_type(16)));

// fp32 -> bf16 bits, round-to-nearest-even (inputs are finite; no NaN path)
__device__ __forceinline__ unsigned short f2bs(float f) {
    unsigned u = __builtin_bit_cast(unsigned, f);
    u = (u + 0x7fffu + ((u >> 16) & 1u)) >> 16;
    return (unsigned short)u;
}
__device__ __forceinline__ float bs2f(unsigned short s) {
    unsigned u = ((unsigned)s) << 16;
    return __builtin_bit_cast(float, u);
}

#define GLDS16(gp, lp)                                                        \
    __builtin_amdgcn_global_load_lds(                                         \
        (const __attribute__((address_space(1))) void*)(gp),                  \
        (__attribute__((address_space(3))) void*)(lp), 16, 0, 0)

#define TCHUNK 32

// ---------------------------------------------------------------------------
// Kernel 1a: per-chunk sums + write the h-half of X in bf16.
// ---------------------------------------------------------------------------
__global__ __launch_bounds__(256) void feats_partial(
    const float* __restrict__ h, float* __restrict__ partial,
    unsigned short* __restrict__ X, int B, int T, int D, int nC) {
    const int d = blockIdx.z * 256 + threadIdx.x;
    const int b = blockIdx.x, c = blockIdx.y;
    const int t0 = c * TCHUNK;
    const int t1 = min(t0 + TCHUNK, T);
    const float* hp = h + ((long)b * T + t0) * D + d;
    unsigned short* xp = X + ((long)b * T + t0) * (2 * D) + D + d;
    float s = 0.f;
    for (int t = t0; t < t1; ++t) {
        float v = *hp;
        *xp = f2bs(v);
        s += v;
        hp += D;
        xp += 2 * D;
    }
    partial[((long)b * nC + c) * D + d] = s;
}

// ---------------------------------------------------------------------------
// Kernel 1b: write the prefix-mean half.
// R14 fix (kept): running sum reads h (fp32, distinct restrict pointer)
// instead of the bf16 X.h readback — the old xp[0]-store/xp[D]-load pair
// was a same-pointer dependence that serialized the t-loop. ~25-30us saved
// (R14 total delta vs GEMM-only delta). Also closer to the fp32 reference.
// ---------------------------------------------------------------------------
__global__ __launch_bounds__(256) void feats_write(
    const float* __restrict__ h, const float* __restrict__ partial,
    unsigned short* __restrict__ X, int B, int T, int D, int nC) {
    const int d = blockIdx.z * 256 + threadIdx.x;
    const int b = blockIdx.x, c = blockIdx.y;
    const int t0 = c * TCHUNK;
    const int t1 = min(t0 + TCHUNK, T);
    float sum = 0.f;
    for (int cc = 0; cc < c; ++cc)
        sum += partial[((long)b * nC + cc) * D + d];
    const float* hp = h + ((long)b * T + t0) * D + d;
    unsigned short* xp = X + ((long)b * T + t0) * (2 * D) + d;
    for (int t = t0; t < t1; ++t) {
        float pm = (t == 0) ? 0.f : sum / (float)t;
        xp[0] = f2bs(pm);
        sum += *hp;
        hp += D;
        xp += 2 * D;
    }
}

// ---------------------------------------------------------------------------
// Kernel 2: transpose + cast. W: [K][N] fp32 -> WT: [N][K] bf16 bits.
// ---------------------------------------------------------------------------
__global__ __launch_bounds__(256) void transpose_cast(
    const float* __restrict__ W, unsigned short* __restrict__ WT,
    int K, int N) {
    __shared__ float tile[32][33];
    const int n0 = blockIdx.x * 32, k0 = blockIdx.y * 32;
    const int tx = threadIdx.x, ty = threadIdx.y;
    #pragma unroll
    for (int i = ty; i < 32; i += 8)
        tile[i][tx] = W[(long)(k0 + i) * N + n0 + tx];
    __syncthreads();
    #pragma unroll
    for (int i = ty; i < 32; i += 8)
        WT[(long)(n0 + i) * K + k0 + tx] = f2bs(tile[tx][i]);
}

// ---------------------------------------------------------------------------
// Kernel 2b: out[m] = b3 (init for the fused-head atomics)
// ---------------------------------------------------------------------------
__global__ __launch_bounds__(256) void init_out(
    float* __restrict__ out, const float* __restrict__ b3, int M) {
    int m = blockIdx.x * 256 + threadIdx.x;
    if (m < M) out[m] = b3[0];
}

// ---------------------------------------------------------------------------
// Kernel 3: GEMM  C[M,N] = relu(A[M,K] * BT[N,K]^T + bias)
//
// R15 = R13 (best: 211us, MfmaUtil 44.3%) + split vmcnt gate.
//
// LAYOUT VERDICT (R14): frag-major LDS drove SQ_LDS_BANK_CONFLICT to 0.0
// and REGRESSED 211->259us (34.6%): LDS read conflicts are NOT on the
// critical path (their full removal bought nothing); the staging side is
// (frag-major forces 32-row x 32B gathers, 2x VMEM requests -> slower
// stages -> longer gate waits). KEEP row-major 64B-segment staging; the
// 1.87e7 conflict counter is benign — do not steer by it again.
//
// SPLIT GATE (this round's one lever): R13's vmcnt(6) waited for ALL of
// tile t incl. Kh1(t), which stretch 3 first reads. Now:
//   gate (pre-BAR, stretch 1) = vmcnt(10): drains Kh0(t) only
//   mid-gate (post mid-BAR)   = vmcnt(8):  drains Kh1(t) before plane-1 read
// Steady-state count audit (2 loads/stage): at gate 14 outstanding
// {Kh0(t) 4 | Kh1(t) 4 | Kh0(t+1) 4 | A-Kh1(t+1) 2}; at mid +stageB = 12.
// Prologue t=0 and tails t=NT-2/NT-1 hand-verified. Strictly less waiting;
// no structural change. If NULL: gates are instant -> residual gap is
// intra-stretch read/MFMA serialization -> next lever is reg-staged B.
//
// SCHEDULE: R11/R13 3-barrier K-tile (R12 lesson: post-gate stage bursts
// regress; keep stages distributed). MODEL: mfma_32x32x16 = 32 cy/SIMD;
// 2048 cy MFMA floor per K-tile; measured 44% => ~2.6k cy/K-tile exposed.
// REGISTER MODEL: 128 acc + ~104 arch = 232 < 256 cliff -> 2 waves/SIMD.
// Reg-staging experiments must budget against the 24-reg headroom (R8).
// LESSONS kept: no min-waves launch_bounds (R4); <=128 acc (R8); C/D
// col=lane&31, row=(reg&3)+8*(reg>>2)+4*(lane>>5) (m74/m101); row-supertile
// XCD map (R11, FETCH 402->179MB); feats_write h-read (R14).
// ---------------------------------------------------------------------------

#define PH_READS(c, ks, AF, BF)                                               \
    _Pragma("unroll")                                                         \
    for (int m_ = 0; m_ < 4; ++m_)                                            \
        AF[m_] = *(const bf16x8*)(&lds[c][0][(ks) >> 1][0] +                  \
                                  (baseA[m_] ^ (16 * ((ks) & 1))));           \
    _Pragma("unroll")                                                         \
    for (int n_ = 0; n_ < 2; ++n_)                                            \
        BF[n_] = *(const bf16x8*)(&lds[c][1][(ks) >> 1][0] +                  \
                                  (baseB[n_] ^ (16 * ((ks) & 1))));

#define PH_MFMA(AF, BF)                                                       \
    __builtin_amdgcn_s_setprio(1);                                            \
    _Pragma("unroll")                                                         \
    for (int m_ = 0; m_ < 4; ++m_)                                            \
        _Pragma("unroll")                                                     \
        for (int n_ = 0; n_ < 2; ++n_)                                        \
            acc[m_][n_] = __builtin_amdgcn_mfma_f32_32x32x16_bf16(            \
                AF[m_], BF[n_], acc[m_][n_], 0, 0, 0);                        \
    __builtin_amdgcn_s_setprio(0);

#define PH(c, ks)                                                             \
    {                                                                         \
        bf16x8 af[4], bfr[2];                                                 \
        PH_READS(c, ks, af, bfr);                                             \
        PH_MFMA(af, bfr);                                                     \
    }

#define BAR()                                                                 \
    __builtin_amdgcn_sched_barrier(0);                                        \
    __builtin_amdgcn_s_barrier();                                             \
    __builtin_amdgcn_sched_barrier(0);

#define GROUP(c, o, t)                                                        \
  {                                                                           \
    /* stretch 1: stage next A-Kh1, gate on Kh0(t) only, sync */              \
    if ((t) + 1 < NT) stageA(o, 1, (t) + 1);                                  \
    if ((t) == NT - 1)                                                        \
        asm volatile("s_waitcnt vmcnt(0)" ::: "memory");                      \
    else                                                                      \
        asm volatile("s_waitcnt vmcnt(10)" ::: "memory");                     \
    BAR();                                                                    \
    /* stretch 2: ks0 + ks1 on Kh0; stage next B-Kh1 */                       \
    PH(c, 0);                                                                 \
    if ((t) + 1 < NT) stageB(o, 1, (t) + 1);                                  \
    PH(c, 1);                                                                 \
    BAR();                                                                    \
    /* mid-gate: Kh1(t) landed before any plane-1 read */                     \
    if ((t) != NT - 1)                                                        \
        asm volatile("s_waitcnt vmcnt(8)" ::: "memory");                      \
    /* stretch 3: ks2 + ks3 on Kh1; stage Kh0(t+2) into freed planes */       \
    if ((t) + 2 < NT) stageA(c, 0, (t) + 2);                                  \
    PH(c, 2);                                                                 \
    if ((t) + 2 < NT) stageB(c, 0, (t) + 2);                                  \
    PH(c, 3);                                                                 \
    BAR();                                                                    \
  }

template <bool FUSE>
__global__ __launch_bounds__(512) void gemm_bt_bias_relu(
    const unsigned short* __restrict__ A,   // [M,K] bf16 bits
    const unsigned short* __restrict__ BT,  // [N,K] bf16 bits
    const float* __restrict__ bias,         // [N]
    unsigned short* __restrict__ C,         // [M,N] bf16 bits (unused if FUSE)
    const float* __restrict__ W3,           // [N] head weights (FUSE only)
    float* __restrict__ outp,               // [M] (FUSE only)
    int M, int N, int K) {
    // [dbuf][A=0/B=1][kh][row*32 + slot*8 .. ] : 128 KiB total
    __shared__ __align__(16) unsigned short lds[2][2][2][8192];

    const int tid = threadIdx.x;
    const int lane = tid & 63;
    const int wave = tid >> 6;
    const int wm = wave >> 2;   // 0..1 -> rows wm*128..+127
    const int wn = wave & 3;    // 0..3 -> cols wn*64..+63
    const int l31 = lane & 31;
    const int half = lane >> 5;

    // ---- m204 bijective XCD chunking over a row-supertile order ----
    const int nRow = M >> 8;            // 127
    const int nCol = N >> 8;            // 8 (GEMM1) / 4 (GEMM2)
    const int nwg = nRow * nCol;
    const int q = nwg >> 3, r = nwg & 7;
    const int x = blockIdx.x & 7;
    const int sidx = blockIdx.x >> 3;
    const int L = (x < r ? x * (q + 1) : r * (q + 1) + (x - r) * q) + sidx;
    // supertile = 8 row-blocks x nCol col-blocks
    const int perSup = 8 * nCol;
    const int nFull = nRow >> 3;        // 15
    const int fullL = nFull * perSup;
    int row_blk, col_blk;
    if (L < fullL) {
        const int sup = L / perSup;
        const int w = L - sup * perSup;
        row_blk = sup * 8 + (w & 7);
        col_blk = w >> 3;
    } else {
        const int rem = L - fullL;
        const int rt = nRow - nFull * 8;  // 7
        row_blk = nFull * 8 + rem % rt;
        col_blk = rem / rt;
    }
    const long row0 = (long)row_blk * 256;
    const long col0 = (long)col_blk * 256;

    // ---- staging source (pre-swizzled global col, rule 21) ----
    // thread covers 16B chunk: row = tid>>2 (+128 for 2nd load), slot=tid&3.
    // global chunk = slot ^ swz(row), swz(r) = ((r>>1)&3) ^ ((r>>3)&3)
    const int sg = ((tid & 3) ^ ((tid >> 3) & 3) ^ ((tid >> 5) & 3)) * 8;
    const unsigned short* Ab = A + (row0 + (tid >> 2)) * K + sg;
    const unsigned short* Bb = BT + (col0 + (tid >> 2)) * K + sg;

    auto stageA = [&](int c, int kh, int kt) {
        GLDS16(Ab + (long)kt * 64 + kh * 32, &lds[c][0][kh][tid * 8]);
        GLDS16(Ab + (long)128 * K + (long)kt * 64 + kh * 32,
               &lds[c][0][kh][(512 + tid) * 8]);
    };
    auto stageB = [&](int c, int kh, int kt) {
        GLDS16(Bb + (long)kt * 64 + kh * 32, &lds[c][1][kh][tid * 8]);
        GLDS16(Bb + (long)128 * K + (long)kt * 64 + kh * 32,
               &lds[c][1][kh][(512 + tid) * 8]);
    };

    // ---- per-lane LDS read offsets (elements within a plane) ----
    // frag (m, ksub): row = wm*128+m*32+l31, k = ksub*16 + half*8
    // slot = chunk ^ ((row>>1)&3) ^ ((row>>3)&3)
    int baseA[4], baseB[2];
    #pragma unroll
    for (int m = 0; m < 4; ++m) {
        int ra = wm * 128 + m * 32 + l31;
        baseA[m] = ra * 32 + ((half ^ ((ra >> 1) & 3) ^ ((ra >> 3) & 3)) * 8);
    }
    #pragma unroll
    for (int n = 0; n < 2; ++n) {
        int rb = wn * 64 + n * 32 + l31;
        baseB[n] = rb * 32 + ((half ^ ((rb >> 1) & 3) ^ ((rb >> 3) & 3)) * 8);
    }

    f32x16 acc[4][2];
    #pragma unroll
    for (int i = 0; i < 4; ++i)
        #pragma unroll
        for (int j = 0; j < 2; ++j)
            acc[i][j] = (f32x16)(0.f);

    const int NT = K >> 6;  // K-tiles of 64 (24 / 32 here; even)

    // ---- prologue: tile0 (4 units) + tile1 Kh0 (2 units), 12 loads ----
    stageA(0, 0, 0); stageB(0, 0, 0);
    stageA(0, 1, 0); stageB(0, 1, 0);
    stageA(1, 0, 1); stageB(1, 0, 1);

    for (int t = 0; t < NT; t += 2) {
        GROUP(0, 1, t);
        GROUP(1, 0, t + 1);
    }

    // Epilogue. C/D: col=lane&31, row=(reg&3)+8*(reg>>2)+4*half (m74/m101)
    if (!FUSE) {
        float bv[2];
        #pragma unroll
        for (int jt = 0; jt < 2; ++jt)
            bv[jt] = bias[col0 + wn * 64 + jt * 32 + l31];
        #pragma unroll
        for (int it = 0; it < 4; ++it) {
            #pragma unroll
            for (int reg = 0; reg < 16; ++reg) {
                const long row = row0 + wm * 128 + it * 32 + (reg & 3) +
                                 8 * (reg >> 2) + 4 * half;
                #pragma unroll
                for (int jt = 0; jt < 2; ++jt) {
                    const long col = col0 + wn * 64 + jt * 32 + l31;
                    float v = fmaxf(acc[it][jt][reg] + bv[jt], 0.f);
                    C[row * N + col] = f2bs(v);
                }
            }
        }
    } else {
        float w3v[2], bv[2];
        #pragma unroll
        for (int jt = 0; jt < 2; ++jt) {
            const long col = col0 + wn * 64 + jt * 32 + l31;
            w3v[jt] = W3[col];
            bv[jt] = bias[col];
        }
        #pragma unroll
        for (int it = 0; it < 4; ++it) {
            #pragma unroll
            for (int reg = 0; reg < 16; ++reg) {
                float s = 0.f;
                #pragma unroll
                for (int jt = 0; jt < 2; ++jt)
                    s += fmaxf(acc[it][jt][reg] + bv[jt], 0.f) * w3v[jt];
                s += __shfl_xor(s, 1, 64);
                s += __shfl_xor(s, 2, 64);
                s += __shfl_xor(s, 4, 64);
                s += __shfl_xor(s, 8, 64);
                s += __shfl_xor(s, 16, 64);
                if (l31 == 0) {
                    const long row = row0 + wm * 128 + it * 32 + (reg & 3) +
                                     8 * (reg >> 2) + 4 * half;
                    atomicAdd(&outp[row], s);
                }
            }
        }
    }
}

// ---------------------------------------------------------------------------
// Launch
// ---------------------------------------------------------------------------
extern "C" void kernel_launch(void* const* d_in, const int* in_sizes, int n_in,
                              void* d_out, int out_size, void* d_ws,
                              size_t ws_size, hipStream_t stream) {
    const float* h  = (const float*)d_in[0];
    const float* W1 = (const float*)d_in[1];
    const float* b1 = (const float*)d_in[2];
    const float* W2 = (const float*)d_in[3];
    const float* b2 = (const float*)d_in[4];
    const float* W3 = (const float*)d_in[5];
    const float* b3 = (const float*)d_in[6];
    float* out = (float*)d_out;

    const int B = 128, T = 254, D = 768, H = 1024;
    const int M = B * T;        // 32512 = 127 * 256
    const int K1 = 2 * D;       // 1536
    const int N1 = 2 * H;       // 2048
    const int K2 = N1;          // 2048
    const int N2 = H;           // 1024
    const int nC = (T + TCHUNK - 1) / TCHUNK;  // 8

    char* ws = (char*)d_ws;
    size_t off = 0;
    auto alloc = [&](size_t bytes) {
        char* p = ws + off;
        off += (bytes + 255) & ~(size_t)255;
        return p;
    };
    unsigned short* X   = (unsigned short*)alloc((size_t)M * K1 * 2);  // 99.9 MB
    unsigned short* H1  = (unsigned short*)alloc((size_t)M * N1 * 2);  // 133.2 MB
    unsigned short* W1T = (unsigned short*)alloc((size_t)N1 * K1 * 2); // 6.3 MB
    unsigned short* W2T = (unsigned short*)alloc((size_t)N2 * K2 * 2); // 4.2 MB
    float* partial      = (float*)alloc((size_t)B * nC * D * 4);       // 3.1 MB

    dim3 tb(32, 8);
    transpose_cast<<<dim3(N1 / 32, K1 / 32), tb, 0, stream>>>(W1, W1T, K1, N1);
    transpose_cast<<<dim3(N2 / 32, K2 / 32), tb, 0, stream>>>(W2, W2T, K2, N2);

    feats_partial<<<dim3(B, nC, D / 256), 256, 0, stream>>>(
        h, partial, X, B, T, D, nC);
    feats_write<<<dim3(B, nC, D / 256), 256, 0, stream>>>(
        h, partial, X, B, T, D, nC);

    init_out<<<dim3((M + 255) / 256), 256, 0, stream>>>(out, b3, M);

    // 256x256 tiles, 512 threads, 3-barrier K-tile schedule, split gates
    gemm_bt_bias_relu<false><<<dim3((M / 256) * (N1 / 256)), 512, 0, stream>>>(
        X, W1T, b1, H1, nullptr, nullptr, M, N1, K1);
    gemm_bt_bias_relu<true><<<dim3((M / 256) * (N2 / 256)), 512, 0, stream>>>(
        H1, W2T, b2, nullptr, W3, out, M, N2, K2);
}

// Round 7
// 572.969 us; speedup vs baseline: 1.0716x; 1.0103x over previous
//
#include <hip/hip_runtime.h>
#include <hip/hip_bf16.h>

// ---------------------------------------------------------------------------
// Types / helpers
// ---------------------------------------------------------------------------
typedef __bf16 bf16x8 __attribute__((ext_vector_type(8)));
typedef float f32x16 __attribute__((ext_vector_type(16)));
typedef float f32x4 __attribute__((ext_vector_type(4)));
typedef unsigned short u16x4 __attribute__((ext_vector_type(4)));

// fp32 -> bf16 bits, round-to-nearest-even (inputs are finite; no NaN path)
__device__ __forceinline__ unsigned short f2bs(float f) {
    unsigned u = __builtin_bit_cast(unsigned, f);
    u = (u + 0x7fffu + ((u >> 16) & 1u)) >> 16;
    return (unsigned short)u;
}
__device__ __forceinline__ float bs2f(unsigned short s) {
    unsigned u = ((unsigned)s) << 16;
    return __builtin_bit_cast(float, u);
}

#define GLDS16(gp, lp)                                                        \
    __builtin_amdgcn_global_load_lds(                                         \
        (const __attribute__((address_space(1))) void*)(gp),                  \
        (__attribute__((address_space(3))) void*)(lp), 16, 0, 0)

#define TCHUNK 32

// ---------------------------------------------------------------------------
// R16: non-GEMM section was ~190us vs ~60us roofline across ALL rounds
// (totals minus GEMM estimates). Cause: scalar 4B loads / 2B stores per
// lane (Common-mistake #2 / G13 — hipcc never vectorizes). Both feats
// kernels now vectorized x4: thread owns 4 consecutive d, float4 loads
// (16B/lane), ushort4 stores (8B/lane). Block 192 (3 waves, D=768/4),
// grid (B, nC). Same parallelism (12 waves/CU), 4x fewer mem insts.
// ---------------------------------------------------------------------------

// Kernel 1a: per-chunk sums + write the h-half of X in bf16. Vectorized x4.
__global__ __launch_bounds__(192) void feats_partial(
    const float* __restrict__ h, float* __restrict__ partial,
    unsigned short* __restrict__ X, int B, int T, int D, int nC) {
    const int d4 = threadIdx.x * 4;       // 0..764
    const int b = blockIdx.x, c = blockIdx.y;
    const int t0 = c * TCHUNK;
    const int t1 = min(t0 + TCHUNK, T);
    const float* hp = h + ((long)b * T + t0) * D + d4;
    unsigned short* xp = X + ((long)b * T + t0) * (2 * D) + D + d4;
    f32x4 s = {0.f, 0.f, 0.f, 0.f};
    for (int t = t0; t < t1; ++t) {
        f32x4 v = *(const f32x4*)hp;
        u16x4 o;
        #pragma unroll
        for (int i = 0; i < 4; ++i) o[i] = f2bs(v[i]);
        *(u16x4*)xp = o;
        s += v;
        hp += D;
        xp += 2 * D;
    }
    *(f32x4*)(partial + ((long)b * nC + c) * D + d4) = s;
}

// Kernel 1b: write the prefix-mean half. Vectorized x4.
// R14 fix kept: running sum reads h (fp32, distinct restrict pointer), not
// the bf16 X readback (same-pointer dependence serialized the loop).
// One reciprocal per t (shared by the 4 d's), not a division per element.
__global__ __launch_bounds__(192) void feats_write(
    const float* __restrict__ h, const float* __restrict__ partial,
    unsigned short* __restrict__ X, int B, int T, int D, int nC) {
    const int d4 = threadIdx.x * 4;
    const int b = blockIdx.x, c = blockIdx.y;
    const int t0 = c * TCHUNK;
    const int t1 = min(t0 + TCHUNK, T);
    f32x4 sum = {0.f, 0.f, 0.f, 0.f};
    for (int cc = 0; cc < c; ++cc)
        sum += *(const f32x4*)(partial + ((long)b * nC + cc) * D + d4);
    const float* hp = h + ((long)b * T + t0) * D + d4;
    unsigned short* xp = X + ((long)b * T + t0) * (2 * D) + d4;
    for (int t = t0; t < t1; ++t) {
        const float inv = (t == 0) ? 0.f : 1.0f / (float)t;
        u16x4 o;
        #pragma unroll
        for (int i = 0; i < 4; ++i) o[i] = f2bs(sum[i] * inv);
        *(u16x4*)xp = o;
        f32x4 v = *(const f32x4*)hp;
        sum += v;
        hp += D;
        xp += 2 * D;
    }
}

// ---------------------------------------------------------------------------
// Kernel 2: transpose + cast. W: [K][N] fp32 -> WT: [N][K] bf16 bits.
// ---------------------------------------------------------------------------
__global__ __launch_bounds__(256) void transpose_cast(
    const float* __restrict__ W, unsigned short* __restrict__ WT,
    int K, int N) {
    __shared__ float tile[32][33];
    const int n0 = blockIdx.x * 32, k0 = blockIdx.y * 32;
    const int tx = threadIdx.x, ty = threadIdx.y;
    #pragma unroll
    for (int i = ty; i < 32; i += 8)
        tile[i][tx] = W[(long)(k0 + i) * N + n0 + tx];
    __syncthreads();
    #pragma unroll
    for (int i = ty; i < 32; i += 8)
        WT[(long)(n0 + i) * K + k0 + tx] = f2bs(tile[tx][i]);
}

// ---------------------------------------------------------------------------
// Kernel 2b: out[m] = b3 (init for the fused-head atomics)
// ---------------------------------------------------------------------------
__global__ __launch_bounds__(256) void init_out(
    float* __restrict__ out, const float* __restrict__ b3, int M) {
    int m = blockIdx.x * 256 + threadIdx.x;
    if (m < M) out[m] = b3[0];
}

// ---------------------------------------------------------------------------
// Kernel 3: GEMM  C[M,N] = relu(A[M,K] * BT[N,K]^T + bias)
//
// R16 GEMM = EXACT R13 (best measured: 211.0us, MfmaUtil 44.3%). FROZEN.
// Schedule-perturbation ledger (all regressed ~7%, all reverted):
//   R12 2-barrier merge        -> 227us / 40.8%
//   R14 frag-major LDS         -> 259us / 34.6% (conflicts 0 but staging
//        gathers 32-row x 32B = 2x VMEM requests; conflicts are BENIGN)
//   R15 split vmcnt gate 10/8  -> 227us / 40.5% (waits LESS, still loses:
//        codegen-sensitive optimum; extra asm sched regions cost more
//        than relaxed waits save)
// Do not touch the K-loop structure again without a fundamentally new
// mechanism (e.g. producer-consumer wave specialization).
//
// Structure: 256x256 tile, BK=64, 512 threads (8 waves 2Mx4N), 3 barriers
// per K-tile, single vmcnt(6) gate, setprio(1) around MFMA clusters,
// double-XOR LDS swizzle slot=ch^((r>>1)&3)^((r>>3)&3) both-sides (rule 21),
// row-supertile XCD map (m204 bijective; FETCH 402->179MB).
// MODEL: mfma_32x32x16 = 32 cy/SIMD; 2048cy MFMA floor/K-tile; 44% =>
// ~2.6k cy/K-tile exposed latency+sync. 128 acc + 104 arch -> 2 waves/SIMD.
// C/D layout col=lane&31, row=(reg&3)+8*(reg>>2)+4*(lane>>5) (m74/m101).
// ---------------------------------------------------------------------------

#define PH_READS(c, ks, AF, BF)                                               \
    _Pragma("unroll")                                                         \
    for (int m_ = 0; m_ < 4; ++m_)                                            \
        AF[m_] = *(const bf16x8*)(&lds[c][0][(ks) >> 1][0] +                  \
                                  (baseA[m_] ^ (16 * ((ks) & 1))));           \
    _Pragma("unroll")                                                         \
    for (int n_ = 0; n_ < 2; ++n_)                                            \
        BF[n_] = *(const bf16x8*)(&lds[c][1][(ks) >> 1][0] +                  \
                                  (baseB[n_] ^ (16 * ((ks) & 1))));

#define PH_MFMA(AF, BF)                                                       \
    __builtin_amdgcn_s_setprio(1);                                            \
    _Pragma("unroll")                                                         \
    for (int m_ = 0; m_ < 4; ++m_)                                            \
        _Pragma("unroll")                                                     \
        for (int n_ = 0; n_ < 2; ++n_)                                        \
            acc[m_][n_] = __builtin_amdgcn_mfma_f32_32x32x16_bf16(            \
                AF[m_], BF[n_], acc[m_][n_], 0, 0, 0);                        \
    __builtin_amdgcn_s_setprio(0);

#define PH(c, ks)                                                             \
    {                                                                         \
        bf16x8 af[4], bfr[2];                                                 \
        PH_READS(c, ks, af, bfr);                                             \
        PH_MFMA(af, bfr);                                                     \
    }

#define BAR()                                                                 \
    __builtin_amdgcn_sched_barrier(0);                                        \
    __builtin_amdgcn_s_barrier();                                             \
    __builtin_amdgcn_sched_barrier(0);

#define GROUP(c, o, t)                                                        \
  {                                                                           \
    /* stretch 1: stage next A-Kh1, gate on tile t, sync */                   \
    if ((t) + 1 < NT) stageA(o, 1, (t) + 1);                                  \
    if ((t) == NT - 1)                                                        \
        asm volatile("s_waitcnt vmcnt(0)" ::: "memory");                      \
    else                                                                      \
        asm volatile("s_waitcnt vmcnt(6)" ::: "memory");                      \
    BAR();                                                                    \
    /* stretch 2: ks0 + ks1 on Kh0; stage next B-Kh1 */                       \
    PH(c, 0);                                                                 \
    if ((t) + 1 < NT) stageB(o, 1, (t) + 1);                                  \
    PH(c, 1);                                                                 \
    BAR();                                                                    \
    /* stretch 3: ks2 + ks3 on Kh1; stage Kh0(t+2) into freed planes */       \
    if ((t) + 2 < NT) stageA(c, 0, (t) + 2);                                  \
    PH(c, 2);                                                                 \
    if ((t) + 2 < NT) stageB(c, 0, (t) + 2);                                  \
    PH(c, 3);                                                                 \
    BAR();                                                                    \
  }

template <bool FUSE>
__global__ __launch_bounds__(512) void gemm_bt_bias_relu(
    const unsigned short* __restrict__ A,   // [M,K] bf16 bits
    const unsigned short* __restrict__ BT,  // [N,K] bf16 bits
    const float* __restrict__ bias,         // [N]
    unsigned short* __restrict__ C,         // [M,N] bf16 bits (unused if FUSE)
    const float* __restrict__ W3,           // [N] head weights (FUSE only)
    float* __restrict__ outp,               // [M] (FUSE only)
    int M, int N, int K) {
    // [dbuf][A=0/B=1][kh][row*32 + slot*8 .. ] : 128 KiB total
    __shared__ __align__(16) unsigned short lds[2][2][2][8192];

    const int tid = threadIdx.x;
    const int lane = tid & 63;
    const int wave = tid >> 6;
    const int wm = wave >> 2;   // 0..1 -> rows wm*128..+127
    const int wn = wave & 3;    // 0..3 -> cols wn*64..+63
    const int l31 = lane & 31;
    const int half = lane >> 5;

    // ---- m204 bijective XCD chunking over a row-supertile order ----
    const int nRow = M >> 8;            // 127
    const int nCol = N >> 8;            // 8 (GEMM1) / 4 (GEMM2)
    const int nwg = nRow * nCol;
    const int q = nwg >> 3, r = nwg & 7;
    const int x = blockIdx.x & 7;
    const int sidx = blockIdx.x >> 3;
    const int L = (x < r ? x * (q + 1) : r * (q + 1) + (x - r) * q) + sidx;
    // supertile = 8 row-blocks x nCol col-blocks
    const int perSup = 8 * nCol;
    const int nFull = nRow >> 3;        // 15
    const int fullL = nFull * perSup;
    int row_blk, col_blk;
    if (L < fullL) {
        const int sup = L / perSup;
        const int w = L - sup * perSup;
        row_blk = sup * 8 + (w & 7);
        col_blk = w >> 3;
    } else {
        const int rem = L - fullL;
        const int rt = nRow - nFull * 8;  // 7
        row_blk = nFull * 8 + rem % rt;
        col_blk = rem / rt;
    }
    const long row0 = (long)row_blk * 256;
    const long col0 = (long)col_blk * 256;

    // ---- staging source (pre-swizzled global col, rule 21) ----
    // thread covers 16B chunk: row = tid>>2 (+128 for 2nd load), slot=tid&3.
    // global chunk = slot ^ swz(row), swz(r) = ((r>>1)&3) ^ ((r>>3)&3)
    const int sg = ((tid & 3) ^ ((tid >> 3) & 3) ^ ((tid >> 5) & 3)) * 8;
    const unsigned short* Ab = A + (row0 + (tid >> 2)) * K + sg;
    const unsigned short* Bb = BT + (col0 + (tid >> 2)) * K + sg;

    auto stageA = [&](int c, int kh, int kt) {
        GLDS16(Ab + (long)kt * 64 + kh * 32, &lds[c][0][kh][tid * 8]);
        GLDS16(Ab + (long)128 * K + (long)kt * 64 + kh * 32,
               &lds[c][0][kh][(512 + tid) * 8]);
    };
    auto stageB = [&](int c, int kh, int kt) {
        GLDS16(Bb + (long)kt * 64 + kh * 32, &lds[c][1][kh][tid * 8]);
        GLDS16(Bb + (long)128 * K + (long)kt * 64 + kh * 32,
               &lds[c][1][kh][(512 + tid) * 8]);
    };

    // ---- per-lane LDS read offsets (elements within a plane) ----
    // frag (m, ksub): row = wm*128+m*32+l31, k = ksub*16 + half*8
    // slot = chunk ^ ((row>>1)&3) ^ ((row>>3)&3)
    int baseA[4], baseB[2];
    #pragma unroll
    for (int m = 0; m < 4; ++m) {
        int ra = wm * 128 + m * 32 + l31;
        baseA[m] = ra * 32 + ((half ^ ((ra >> 1) & 3) ^ ((ra >> 3) & 3)) * 8);
    }
    #pragma unroll
    for (int n = 0; n < 2; ++n) {
        int rb = wn * 64 + n * 32 + l31;
        baseB[n] = rb * 32 + ((half ^ ((rb >> 1) & 3) ^ ((rb >> 3) & 3)) * 8);
    }

    f32x16 acc[4][2];
    #pragma unroll
    for (int i = 0; i < 4; ++i)
        #pragma unroll
        for (int j = 0; j < 2; ++j)
            acc[i][j] = (f32x16)(0.f);

    const int NT = K >> 6;  // K-tiles of 64 (24 / 32 here; even)

    // ---- prologue: tile0 (4 units) + tile1 Kh0 (2 units), 12 loads ----
    stageA(0, 0, 0); stageB(0, 0, 0);
    stageA(0, 1, 0); stageB(0, 1, 0);
    stageA(1, 0, 1); stageB(1, 0, 1);

    for (int t = 0; t < NT; t += 2) {
        GROUP(0, 1, t);
        GROUP(1, 0, t + 1);
    }

    // Epilogue. C/D: col=lane&31, row=(reg&3)+8*(reg>>2)+4*half (m74/m101)
    if (!FUSE) {
        float bv[2];
        #pragma unroll
        for (int jt = 0; jt < 2; ++jt)
            bv[jt] = bias[col0 + wn * 64 + jt * 32 + l31];
        #pragma unroll
        for (int it = 0; it < 4; ++it) {
            #pragma unroll
            for (int reg = 0; reg < 16; ++reg) {
                const long row = row0 + wm * 128 + it * 32 + (reg & 3) +
                                 8 * (reg >> 2) + 4 * half;
                #pragma unroll
                for (int jt = 0; jt < 2; ++jt) {
                    const long col = col0 + wn * 64 + jt * 32 + l31;
                    float v = fmaxf(acc[it][jt][reg] + bv[jt], 0.f);
                    C[row * N + col] = f2bs(v);
                }
            }
        }
    } else {
        float w3v[2], bv[2];
        #pragma unroll
        for (int jt = 0; jt < 2; ++jt) {
            const long col = col0 + wn * 64 + jt * 32 + l31;
            w3v[jt] = W3[col];
            bv[jt] = bias[col];
        }
        #pragma unroll
        for (int it = 0; it < 4; ++it) {
            #pragma unroll
            for (int reg = 0; reg < 16; ++reg) {
                float s = 0.f;
                #pragma unroll
                for (int jt = 0; jt < 2; ++jt)
                    s += fmaxf(acc[it][jt][reg] + bv[jt], 0.f) * w3v[jt];
                s += __shfl_xor(s, 1, 64);
                s += __shfl_xor(s, 2, 64);
                s += __shfl_xor(s, 4, 64);
                s += __shfl_xor(s, 8, 64);
                s += __shfl_xor(s, 16, 64);
                if (l31 == 0) {
                    const long row = row0 + wm * 128 + it * 32 + (reg & 3) +
                                     8 * (reg >> 2) + 4 * half;
                    atomicAdd(&outp[row], s);
                }
            }
        }
    }
}

// ---------------------------------------------------------------------------
// Launch
// ---------------------------------------------------------------------------
extern "C" void kernel_launch(void* const* d_in, const int* in_sizes, int n_in,
                              void* d_out, int out_size, void* d_ws,
                              size_t ws_size, hipStream_t stream) {
    const float* h  = (const float*)d_in[0];
    const float* W1 = (const float*)d_in[1];
    const float* b1 = (const float*)d_in[2];
    const float* W2 = (const float*)d_in[3];
    const float* b2 = (const float*)d_in[4];
    const float* W3 = (const float*)d_in[5];
    const float* b3 = (const float*)d_in[6];
    float* out = (float*)d_out;

    const int B = 128, T = 254, D = 768, H = 1024;
    const int M = B * T;        // 32512 = 127 * 256
    const int K1 = 2 * D;       // 1536
    const int N1 = 2 * H;       // 2048
    const int K2 = N1;          // 2048
    const int N2 = H;           // 1024
    const int nC = (T + TCHUNK - 1) / TCHUNK;  // 8

    char* ws = (char*)d_ws;
    size_t off = 0;
    auto alloc = [&](size_t bytes) {
        char* p = ws + off;
        off += (bytes + 255) & ~(size_t)255;
        return p;
    };
    unsigned short* X   = (unsigned short*)alloc((size_t)M * K1 * 2);  // 99.9 MB
    unsigned short* H1  = (unsigned short*)alloc((size_t)M * N1 * 2);  // 133.2 MB
    unsigned short* W1T = (unsigned short*)alloc((size_t)N1 * K1 * 2); // 6.3 MB
    unsigned short* W2T = (unsigned short*)alloc((size_t)N2 * K2 * 2); // 4.2 MB
    float* partial      = (float*)alloc((size_t)B * nC * D * 4);       // 3.1 MB

    dim3 tb(32, 8);
    transpose_cast<<<dim3(N1 / 32, K1 / 32), tb, 0, stream>>>(W1, W1T, K1, N1);
    transpose_cast<<<dim3(N2 / 32, K2 / 32), tb, 0, stream>>>(W2, W2T, K2, N2);

    // vectorized x4: block 192 threads (3 waves), thread owns 4 d's
    feats_partial<<<dim3(B, nC), 192, 0, stream>>>(h, partial, X, B, T, D, nC);
    feats_write<<<dim3(B, nC), 192, 0, stream>>>(h, partial, X, B, T, D, nC);

    init_out<<<dim3((M + 255) / 256), 256, 0, stream>>>(out, b3, M);

    // 256x256 tiles, 512 threads, R13 3-barrier K-tile schedule (frozen)
    gemm_bt_bias_relu<false><<<dim3((M / 256) * (N1 / 256)), 512, 0, stream>>>(
        X, W1T, b1, H1, nullptr, nullptr, M, N1, K1);
    gemm_bt_bias_relu<true><<<dim3((M / 256) * (N2 / 256)), 512, 0, stream>>>(
        H1, W2T, b2, nullptr, W3, out, M, N2, K2);
}

// Round 8
// 529.191 us; speedup vs baseline: 1.1603x; 1.0827x over previous
//
#include <hip/hip_runtime.h>
#include <hip/hip_bf16.h>

// ---------------------------------------------------------------------------
// Types / helpers
// ---------------------------------------------------------------------------
typedef __bf16 bf16x8 __attribute__((ext_vector_type(8)));
typedef float f32x4 __attribute__((ext_vector_type(4)));
typedef unsigned short u16x4 __attribute__((ext_vector_type(4)));

// fp32 -> bf16 bits, round-to-nearest-even (inputs are finite; no NaN path)
__device__ __forceinline__ unsigned short f2bs(float f) {
    unsigned u = __builtin_bit_cast(unsigned, f);
    u = (u + 0x7fffu + ((u >> 16) & 1u)) >> 16;
    return (unsigned short)u;
}
__device__ __forceinline__ float bs2f(unsigned short s) {
    unsigned u = ((unsigned)s) << 16;
    return __builtin_bit_cast(float, u);
}

#define GLDS16(gp, lp)                                                        \
    __builtin_amdgcn_global_load_lds(                                         \
        (const __attribute__((address_space(1))) void*)(gp),                  \
        (__attribute__((address_space(3))) void*)(lp), 16, 0, 0)

#define TCHUNK 32

// ---------------------------------------------------------------------------
// feats kernels: vectorized x4 (R16; measured null vs scalar — kept, benign).
// R14 h-read fix kept (aliasing serialized the old bf16 readback loop).
// NOTE (R16 ledger): non-GEMM time did not respond to vectorization ->
// not memory-instruction-bound; stop iterating here.
// ---------------------------------------------------------------------------
__global__ __launch_bounds__(192) void feats_partial(
    const float* __restrict__ h, float* __restrict__ partial,
    unsigned short* __restrict__ X, int B, int T, int D, int nC) {
    const int d4 = threadIdx.x * 4;       // 0..764
    const int b = blockIdx.x, c = blockIdx.y;
    const int t0 = c * TCHUNK;
    const int t1 = min(t0 + TCHUNK, T);
    const float* hp = h + ((long)b * T + t0) * D + d4;
    unsigned short* xp = X + ((long)b * T + t0) * (2 * D) + D + d4;
    f32x4 s = {0.f, 0.f, 0.f, 0.f};
    for (int t = t0; t < t1; ++t) {
        f32x4 v = *(const f32x4*)hp;
        u16x4 o;
        #pragma unroll
        for (int i = 0; i < 4; ++i) o[i] = f2bs(v[i]);
        *(u16x4*)xp = o;
        s += v;
        hp += D;
        xp += 2 * D;
    }
    *(f32x4*)(partial + ((long)b * nC + c) * D + d4) = s;
}

__global__ __launch_bounds__(192) void feats_write(
    const float* __restrict__ h, const float* __restrict__ partial,
    unsigned short* __restrict__ X, int B, int T, int D, int nC) {
    const int d4 = threadIdx.x * 4;
    const int b = blockIdx.x, c = blockIdx.y;
    const int t0 = c * TCHUNK;
    const int t1 = min(t0 + TCHUNK, T);
    f32x4 sum = {0.f, 0.f, 0.f, 0.f};
    for (int cc = 0; cc < c; ++cc)
        sum += *(const f32x4*)(partial + ((long)b * nC + cc) * D + d4);
    const float* hp = h + ((long)b * T + t0) * D + d4;
    unsigned short* xp = X + ((long)b * T + t0) * (2 * D) + d4;
    for (int t = t0; t < t1; ++t) {
        const float inv = (t == 0) ? 0.f : 1.0f / (float)t;
        u16x4 o;
        #pragma unroll
        for (int i = 0; i < 4; ++i) o[i] = f2bs(sum[i] * inv);
        *(u16x4*)xp = o;
        f32x4 v = *(const f32x4*)hp;
        sum += v;
        hp += D;
        xp += 2 * D;
    }
}

// ---------------------------------------------------------------------------
// Kernel 2: transpose + cast. W: [K][N] fp32 -> WT: [N][K] bf16 bits.
// ---------------------------------------------------------------------------
__global__ __launch_bounds__(256) void transpose_cast(
    const float* __restrict__ W, unsigned short* __restrict__ WT,
    int K, int N) {
    __shared__ float tile[32][33];
    const int n0 = blockIdx.x * 32, k0 = blockIdx.y * 32;
    const int tx = threadIdx.x, ty = threadIdx.y;
    #pragma unroll
    for (int i = ty; i < 32; i += 8)
        tile[i][tx] = W[(long)(k0 + i) * N + n0 + tx];
    __syncthreads();
    #pragma unroll
    for (int i = ty; i < 32; i += 8)
        WT[(long)(n0 + i) * K + k0 + tx] = f2bs(tile[tx][i]);
}

__global__ __launch_bounds__(256) void init_out(
    float* __restrict__ out, const float* __restrict__ b3, int M) {
    int m = blockIdx.x * 256 + threadIdx.x;
    if (m < M) out[m] = b3[0];
}

// ---------------------------------------------------------------------------
// Kernel 3: GEMM  C[M,N] = relu(A[M,K] * BT[N,K]^T + bias)
//
// R17: 16x16x32 MFMA core inside R13's UNCHANGED sync skeleton.
// Rationale: R13 plateau = 44% of the 32x32 pipe (2495 TF ceiling) and 3
// schedule mutations failed. HipKittens/m201 use 16x16x32 with 16-MFMA
// clusters and reach 75-92% of the 2075 TF 16x16 ceiling — shorter-latency
// instructions (19cy vs 32cy), 16 independent accumulates per cluster,
// finer ds_read/MFMA interleave. BREAK-EVEN: util must exceed ~53% (16x16
// ceiling is 17% lower). If util <= ~46% -> revert to R13 (32x32) for good.
//
// UNCHANGED from R13: 256x256 tile, BK=64, 512 thr (8 waves 2Mx4N), LDS
// [dbuf][A|B][plane][256r][32e] w/ double-XOR swizzle both-sides, staging
// (global_load_lds x2/unit), 3 barriers + single vmcnt(6) gate per K-tile,
// stage distribution {A-kh1 pre-gate | B-kh1 mid | A-kh0,B-kh0 stretch3},
// prologue, row-supertile XCD map.
// CHANGED: per plane ks: read B-frags ONCE (4 b128, held), then 2 row-group
// clusters {4 A-reads + 16 mfma_16x16x32}. acc f32x4[8][4] = 128 regs (R8
// cap ok). Frag layout: A/B lane: row=lane&15, k=(lane>>4)*8+j (analog of
// the verified 32x32 pattern). C/D: col=lane&15, row=(lane>>4)*4+reg (m89).
// Epilogue + FUSE head rewritten for 16x16 C/D; FUSE shfl chain now 4 steps
// over 16-lane groups.
// LEDGER: R12 2-bar merge -227us/40.8%; R14 frag-major -259/34.6% (conflict
// counter proven benign); R15 split-gate -227/40.5%; R16 feats-vec null
// (total noise band +-14us). No min-waves bounds (R4); <=128 acc (R8).
// ---------------------------------------------------------------------------

#define RD_A(dst, c, g, ks)                                                   \
    _Pragma("unroll")                                                         \
    for (int fr_ = 0; fr_ < 4; ++fr_)                                         \
        dst[fr_] = *(const bf16x8*)(&lds[(c)][0][(ks)][0] +                   \
                                    baseA16[(g) * 4 + fr_]);

#define RD_B(dst, c, ks)                                                      \
    _Pragma("unroll")                                                         \
    for (int fc_ = 0; fc_ < 4; ++fc_)                                         \
        dst[fc_] = *(const bf16x8*)(&lds[(c)][1][(ks)][0] + baseB16[fc_]);

#define MM16(g, AF, BF)                                                       \
    __builtin_amdgcn_s_setprio(1);                                            \
    _Pragma("unroll")                                                         \
    for (int fr_ = 0; fr_ < 4; ++fr_)                                         \
        _Pragma("unroll")                                                     \
        for (int fc_ = 0; fc_ < 4; ++fc_)                                     \
            acc[(g) * 4 + fr_][fc_] = __builtin_amdgcn_mfma_f32_16x16x32_bf16(\
                AF[fr_], BF[fc_], acc[(g) * 4 + fr_][fc_], 0, 0, 0);          \
    __builtin_amdgcn_s_setprio(0);

#define BAR()                                                                 \
    __builtin_amdgcn_sched_barrier(0);                                        \
    __builtin_amdgcn_s_barrier();                                             \
    __builtin_amdgcn_sched_barrier(0);

#define GROUP(c, o, t)                                                        \
  {                                                                           \
    /* stretch 1: stage next A-Kh1, gate on tile t, sync (R13-exact) */       \
    if ((t) + 1 < NT) stageA(o, 1, (t) + 1);                                  \
    if ((t) == NT - 1)                                                        \
        asm volatile("s_waitcnt vmcnt(0)" ::: "memory");                      \
    else                                                                      \
        asm volatile("s_waitcnt vmcnt(6)" ::: "memory");                      \
    BAR();                                                                    \
    /* stretch 2: plane 0; B read once, 2 row-group clusters */               \
    {                                                                         \
        bf16x8 bfr[4];                                                        \
        RD_B(bfr, c, 0);                                                      \
        {                                                                     \
            bf16x8 af[4];                                                     \
            RD_A(af, c, 0, 0);                                                \
            MM16(0, af, bfr);                                                 \
        }                                                                     \
        if ((t) + 1 < NT) stageB(o, 1, (t) + 1);                              \
        {                                                                     \
            bf16x8 af[4];                                                     \
            RD_A(af, c, 1, 0);                                                \
            MM16(1, af, bfr);                                                 \
        }                                                                     \
    }                                                                         \
    BAR();                                                                    \
    /* stretch 3: plane 1; stage Kh0(t+2) into freed planes */                \
    {                                                                         \
        bf16x8 bfr[4];                                                        \
        if ((t) + 2 < NT) stageA(c, 0, (t) + 2);                              \
        RD_B(bfr, c, 1);                                                      \
        {                                                                     \
            bf16x8 af[4];                                                     \
            RD_A(af, c, 0, 1);                                                \
            MM16(0, af, bfr);                                                 \
        }                                                                     \
        if ((t) + 2 < NT) stageB(c, 0, (t) + 2);                              \
        {                                                                     \
            bf16x8 af[4];                                                     \
            RD_A(af, c, 1, 1);                                                \
            MM16(1, af, bfr);                                                 \
        }                                                                     \
    }                                                                         \
    BAR();                                                                    \
  }

template <bool FUSE>
__global__ __launch_bounds__(512) void gemm_bt_bias_relu(
    const unsigned short* __restrict__ A,   // [M,K] bf16 bits
    const unsigned short* __restrict__ BT,  // [N,K] bf16 bits
    const float* __restrict__ bias,         // [N]
    unsigned short* __restrict__ C,         // [M,N] bf16 bits (unused if FUSE)
    const float* __restrict__ W3,           // [N] head weights (FUSE only)
    float* __restrict__ outp,               // [M] (FUSE only)
    int M, int N, int K) {
    // [dbuf][A=0/B=1][plane][row*32 + slot*8 .. ] : 128 KiB total
    __shared__ __align__(16) unsigned short lds[2][2][2][8192];

    const int tid = threadIdx.x;
    const int lane = tid & 63;
    const int wave = tid >> 6;
    const int wm = wave >> 2;   // 0..1 -> rows wm*128..+127
    const int wn = wave & 3;    // 0..3 -> cols wn*64..+63
    const int l15 = lane & 15;
    const int q4 = lane >> 4;   // 0..3

    // ---- m204 bijective XCD chunking over a row-supertile order ----
    const int nRow = M >> 8;            // 127
    const int nCol = N >> 8;            // 8 (GEMM1) / 4 (GEMM2)
    const int nwg = nRow * nCol;
    const int q = nwg >> 3, r = nwg & 7;
    const int x = blockIdx.x & 7;
    const int sidx = blockIdx.x >> 3;
    const int L = (x < r ? x * (q + 1) : r * (q + 1) + (x - r) * q) + sidx;
    const int perSup = 8 * nCol;
    const int nFull = nRow >> 3;        // 15
    const int fullL = nFull * perSup;
    int row_blk, col_blk;
    if (L < fullL) {
        const int sup = L / perSup;
        const int w = L - sup * perSup;
        row_blk = sup * 8 + (w & 7);
        col_blk = w >> 3;
    } else {
        const int rem = L - fullL;
        const int rt = nRow - nFull * 8;  // 7
        row_blk = nFull * 8 + rem % rt;
        col_blk = rem / rt;
    }
    const long row0 = (long)row_blk * 256;
    const long col0 = (long)col_blk * 256;

    // ---- staging source (pre-swizzled global col, rule 21; R13-exact) ----
    // thread covers 16B chunk: row = tid>>2 (+128 for 2nd load), slot=tid&3.
    // global chunk = slot ^ swz(row), swz(r) = ((r>>1)&3) ^ ((r>>3)&3)
    const int sg = ((tid & 3) ^ ((tid >> 3) & 3) ^ ((tid >> 5) & 3)) * 8;
    const unsigned short* Ab = A + (row0 + (tid >> 2)) * K + sg;
    const unsigned short* Bb = BT + (col0 + (tid >> 2)) * K + sg;

    auto stageA = [&](int c, int kh, int kt) {
        GLDS16(Ab + (long)kt * 64 + kh * 32, &lds[c][0][kh][tid * 8]);
        GLDS16(Ab + (long)128 * K + (long)kt * 64 + kh * 32,
               &lds[c][0][kh][(512 + tid) * 8]);
    };
    auto stageB = [&](int c, int kh, int kt) {
        GLDS16(Bb + (long)kt * 64 + kh * 32, &lds[c][1][kh][tid * 8]);
        GLDS16(Bb + (long)128 * K + (long)kt * 64 + kh * 32,
               &lds[c][1][kh][(512 + tid) * 8]);
    };

    // ---- per-lane LDS read offsets for 16x16 frags ----
    // frag (i, ks): row = wm*128 + i*16 + l15, k = ks*32 + q4*8 + j
    // plane = ks, chunk = q4, slot = chunk ^ ((row>>1)&3) ^ ((row>>3)&3)
    int baseA16[8], baseB16[4];
    #pragma unroll
    for (int i = 0; i < 8; ++i) {
        int ra = wm * 128 + i * 16 + l15;
        baseA16[i] = ra * 32 + ((q4 ^ ((ra >> 1) & 3) ^ ((ra >> 3) & 3)) * 8);
    }
    #pragma unroll
    for (int fc = 0; fc < 4; ++fc) {
        int rb = wn * 64 + fc * 16 + l15;
        baseB16[fc] = rb * 32 + ((q4 ^ ((rb >> 1) & 3) ^ ((rb >> 3) & 3)) * 8);
    }

    f32x4 acc[8][4];
    #pragma unroll
    for (int i = 0; i < 8; ++i)
        #pragma unroll
        for (int j = 0; j < 4; ++j)
            acc[i][j] = (f32x4)(0.f);

    const int NT = K >> 6;  // K-tiles of 64 (24 / 32 here; even)

    // ---- prologue: tile0 (4 units) + tile1 Kh0 (2 units), 12 loads ----
    stageA(0, 0, 0); stageB(0, 0, 0);
    stageA(0, 1, 0); stageB(0, 1, 0);
    stageA(1, 0, 1); stageB(1, 0, 1);

    for (int t = 0; t < NT; t += 2) {
        GROUP(0, 1, t);
        GROUP(1, 0, t + 1);
    }

    // Epilogue. 16x16 C/D: col=lane&15, row=(lane>>4)*4+reg (m89/m91)
    if (!FUSE) {
        float bv[4];
        #pragma unroll
        for (int fc = 0; fc < 4; ++fc)
            bv[fc] = bias[col0 + wn * 64 + fc * 16 + l15];
        #pragma unroll
        for (int fr = 0; fr < 8; ++fr) {
            #pragma unroll
            for (int reg = 0; reg < 4; ++reg) {
                const long row = row0 + wm * 128 + fr * 16 + q4 * 4 + reg;
                #pragma unroll
                for (int fc = 0; fc < 4; ++fc) {
                    const long col = col0 + wn * 64 + fc * 16 + l15;
                    float v = fmaxf(acc[fr][fc][reg] + bv[fc], 0.f);
                    C[row * N + col] = f2bs(v);
                }
            }
        }
    } else {
        float w3v[4], bv[4];
        #pragma unroll
        for (int fc = 0; fc < 4; ++fc) {
            const long col = col0 + wn * 64 + fc * 16 + l15;
            w3v[fc] = W3[col];
            bv[fc] = bias[col];
        }
        #pragma unroll
        for (int fr = 0; fr < 8; ++fr) {
            #pragma unroll
            for (int reg = 0; reg < 4; ++reg) {
                float s = 0.f;
                #pragma unroll
                for (int fc = 0; fc < 4; ++fc)
                    s += fmaxf(acc[fr][fc][reg] + bv[fc], 0.f) * w3v[fc];
                // reduce over the 16 cols held by this 16-lane group
                s += __shfl_xor(s, 1, 64);
                s += __shfl_xor(s, 2, 64);
                s += __shfl_xor(s, 4, 64);
                s += __shfl_xor(s, 8, 64);
                if (l15 == 0) {
                    const long row = row0 + wm * 128 + fr * 16 + q4 * 4 + reg;
                    atomicAdd(&outp[row], s);
                }
            }
        }
    }
}

// ---------------------------------------------------------------------------
// Launch
// ---------------------------------------------------------------------------
extern "C" void kernel_launch(void* const* d_in, const int* in_sizes, int n_in,
                              void* d_out, int out_size, void* d_ws,
                              size_t ws_size, hipStream_t stream) {
    const float* h  = (const float*)d_in[0];
    const float* W1 = (const float*)d_in[1];
    const float* b1 = (const float*)d_in[2];
    const float* W2 = (const float*)d_in[3];
    const float* b2 = (const float*)d_in[4];
    const float* W3 = (const float*)d_in[5];
    const float* b3 = (const float*)d_in[6];
    float* out = (float*)d_out;

    const int B = 128, T = 254, D = 768, H = 1024;
    const int M = B * T;        // 32512 = 127 * 256
    const int K1 = 2 * D;       // 1536
    const int N1 = 2 * H;       // 2048
    const int K2 = N1;          // 2048
    const int N2 = H;           // 1024
    const int nC = (T + TCHUNK - 1) / TCHUNK;  // 8

    char* ws = (char*)d_ws;
    size_t off = 0;
    auto alloc = [&](size_t bytes) {
        char* p = ws + off;
        off += (bytes + 255) & ~(size_t)255;
        return p;
    };
    unsigned short* X   = (unsigned short*)alloc((size_t)M * K1 * 2);  // 99.9 MB
    unsigned short* H1  = (unsigned short*)alloc((size_t)M * N1 * 2);  // 133.2 MB
    unsigned short* W1T = (unsigned short*)alloc((size_t)N1 * K1 * 2); // 6.3 MB
    unsigned short* W2T = (unsigned short*)alloc((size_t)N2 * K2 * 2); // 4.2 MB
    float* partial      = (float*)alloc((size_t)B * nC * D * 4);       // 3.1 MB

    dim3 tb(32, 8);
    transpose_cast<<<dim3(N1 / 32, K1 / 32), tb, 0, stream>>>(W1, W1T, K1, N1);
    transpose_cast<<<dim3(N2 / 32, K2 / 32), tb, 0, stream>>>(W2, W2T, K2, N2);

    feats_partial<<<dim3(B, nC), 192, 0, stream>>>(h, partial, X, B, T, D, nC);
    feats_write<<<dim3(B, nC), 192, 0, stream>>>(h, partial, X, B, T, D, nC);

    init_out<<<dim3((M + 255) / 256), 256, 0, stream>>>(out, b3, M);

    // 256x256 tiles, 512 threads, R13 skeleton + 16x16x32 core
    gemm_bt_bias_relu<false><<<dim3((M / 256) * (N1 / 256)), 512, 0, stream>>>(
        X, W1T, b1, H1, nullptr, nullptr, M, N1, K1);
    gemm_bt_bias_relu<true><<<dim3((M / 256) * (N2 / 256)), 512, 0, stream>>>(
        H1, W2T, b2, nullptr, W3, out, M, N2, K2);
}

// Round 9
// 519.793 us; speedup vs baseline: 1.1812x; 1.0181x over previous
//
#include <hip/hip_runtime.h>
#include <hip/hip_bf16.h>

// ---------------------------------------------------------------------------
// Types / helpers
// ---------------------------------------------------------------------------
typedef __bf16 bf16x8 __attribute__((ext_vector_type(8)));
typedef float f32x4 __attribute__((ext_vector_type(4)));
typedef unsigned short u16x4 __attribute__((ext_vector_type(4)));

// fp32 -> bf16 bits, round-to-nearest-even (inputs are finite; no NaN path)
__device__ __forceinline__ unsigned short f2bs(float f) {
    unsigned u = __builtin_bit_cast(unsigned, f);
    u = (u + 0x7fffu + ((u >> 16) & 1u)) >> 16;
    return (unsigned short)u;
}
__device__ __forceinline__ float bs2f(unsigned short s) {
    unsigned u = ((unsigned)s) << 16;
    return __builtin_bit_cast(float, u);
}

#define GLDS16(gp, lp)                                                        \
    __builtin_amdgcn_global_load_lds(                                         \
        (const __attribute__((address_space(1))) void*)(gp),                  \
        (__attribute__((address_space(3))) void*)(lp), 16, 0, 0)

// R18: TCHUNK 32 -> 16. Accounting (R17): non-GEMM ~181us vs 63us BW floor;
// R16 proved not instruction-bound -> latency/TLP: (B,8) grid = 12 waves/CU
// and ~1 HBM load in flight per wave. TCHUNK=16 doubles grid (24 waves/CU)
// and halves the serial chain; unroll-4 puts 4 loads in flight (loads are
// independent: distinct restrict ptrs; sum chain is VALU-only).
// Pre-commit: if total unchanged (+-15us), feats latency theory dead ->
// pivot to GEMM2.
#define TCHUNK 16

// Kernel 1a: per-chunk sums + write the h-half of X in bf16. Vectorized x4.
__global__ __launch_bounds__(192) void feats_partial(
    const float* __restrict__ h, float* __restrict__ partial,
    unsigned short* __restrict__ X, int B, int T, int D, int nC) {
    const int d4 = threadIdx.x * 4;       // 0..764
    const int b = blockIdx.x, c = blockIdx.y;
    const int t0 = c * TCHUNK;
    const int t1 = min(t0 + TCHUNK, T);
    const float* hp = h + ((long)b * T + t0) * D + d4;
    unsigned short* xp = X + ((long)b * T + t0) * (2 * D) + D + d4;
    f32x4 s = {0.f, 0.f, 0.f, 0.f};
    #pragma unroll 4
    for (int t = t0; t < t1; ++t) {
        f32x4 v = *(const f32x4*)hp;
        u16x4 o;
        #pragma unroll
        for (int i = 0; i < 4; ++i) o[i] = f2bs(v[i]);
        *(u16x4*)xp = o;
        s += v;
        hp += D;
        xp += 2 * D;
    }
    *(f32x4*)(partial + ((long)b * nC + c) * D + d4) = s;
}

// Kernel 1b: write the prefix-mean half. Vectorized x4.
// R14 fix kept: running sum reads h (fp32, distinct restrict pointer), not
// the bf16 X readback (same-pointer dependence serialized the loop).
__global__ __launch_bounds__(192) void feats_write(
    const float* __restrict__ h, const float* __restrict__ partial,
    unsigned short* __restrict__ X, int B, int T, int D, int nC) {
    const int d4 = threadIdx.x * 4;
    const int b = blockIdx.x, c = blockIdx.y;
    const int t0 = c * TCHUNK;
    const int t1 = min(t0 + TCHUNK, T);
    f32x4 sum = {0.f, 0.f, 0.f, 0.f};
    #pragma unroll 4
    for (int cc = 0; cc < c; ++cc)
        sum += *(const f32x4*)(partial + ((long)b * nC + cc) * D + d4);
    const float* hp = h + ((long)b * T + t0) * D + d4;
    unsigned short* xp = X + ((long)b * T + t0) * (2 * D) + d4;
    #pragma unroll 4
    for (int t = t0; t < t1; ++t) {
        const float inv = (t == 0) ? 0.f : 1.0f / (float)t;
        u16x4 o;
        #pragma unroll
        for (int i = 0; i < 4; ++i) o[i] = f2bs(sum[i] * inv);
        *(u16x4*)xp = o;
        f32x4 v = *(const f32x4*)hp;
        sum += v;
        hp += D;
        xp += 2 * D;
    }
}

// ---------------------------------------------------------------------------
// Kernel 2: transpose + cast. W: [K][N] fp32 -> WT: [N][K] bf16 bits.
// ---------------------------------------------------------------------------
__global__ __launch_bounds__(256) void transpose_cast(
    const float* __restrict__ W, unsigned short* __restrict__ WT,
    int K, int N) {
    __shared__ float tile[32][33];
    const int n0 = blockIdx.x * 32, k0 = blockIdx.y * 32;
    const int tx = threadIdx.x, ty = threadIdx.y;
    #pragma unroll
    for (int i = ty; i < 32; i += 8)
        tile[i][tx] = W[(long)(k0 + i) * N + n0 + tx];
    __syncthreads();
    #pragma unroll
    for (int i = ty; i < 32; i += 8)
        WT[(long)(n0 + i) * K + k0 + tx] = f2bs(tile[tx][i]);
}

__global__ __launch_bounds__(256) void init_out(
    float* __restrict__ out, const float* __restrict__ b3, int M) {
    int m = blockIdx.x * 256 + threadIdx.x;
    if (m < M) out[m] = b3[0];
}

// ---------------------------------------------------------------------------
// Kernel 3: GEMM  C[M,N] = relu(A[M,K] * BT[N,K]^T + bias)
//
// R18 GEMM = EXACT R17 (best: total 529us; GEMM1 209us). FROZEN.
// R17 verdict: 16x16x32 core flat on GEMM1 main loop vs 32x32 (within
// noise) but the cheaper FUSE epilogue (32 iters x 4 shfl vs 64 x 5)
// bought ~30us on GEMM2 -> keep. MfmaUtil no longer comparable across
// shapes (16x16 pipe ceiling 2075 vs 2495 TF); steer by dur_us.
// LEDGER (do not retry): R12 2-bar merge -7%; R14 frag-major LDS -23%
// (bank-conflict counter proven benign); R15 split-gate -7%; R16 feats
// instr-vectorization null. No min-waves bounds (R4); <=128 acc (R8).
// Structure: 256x256 tile, BK=64, 512 thr (8 waves 2Mx4N), R13 3-barrier
// K-tile skeleton, vmcnt(6) gate, setprio, double-XOR swizzle both-sides,
// row-supertile XCD map. Frag: A/B row=lane&15, k=(lane>>4)*8+j; C/D
// col=lane&15, row=(lane>>4)*4+reg (m89/m91).
// ---------------------------------------------------------------------------

#define RD_A(dst, c, g, ks)                                                   \
    _Pragma("unroll")                                                         \
    for (int fr_ = 0; fr_ < 4; ++fr_)                                         \
        dst[fr_] = *(const bf16x8*)(&lds[(c)][0][(ks)][0] +                   \
                                    baseA16[(g) * 4 + fr_]);

#define RD_B(dst, c, ks)                                                      \
    _Pragma("unroll")                                                         \
    for (int fc_ = 0; fc_ < 4; ++fc_)                                         \
        dst[fc_] = *(const bf16x8*)(&lds[(c)][1][(ks)][0] + baseB16[fc_]);

#define MM16(g, AF, BF)                                                       \
    __builtin_amdgcn_s_setprio(1);                                            \
    _Pragma("unroll")                                                         \
    for (int fr_ = 0; fr_ < 4; ++fr_)                                         \
        _Pragma("unroll")                                                     \
        for (int fc_ = 0; fc_ < 4; ++fc_)                                     \
            acc[(g) * 4 + fr_][fc_] = __builtin_amdgcn_mfma_f32_16x16x32_bf16(\
                AF[fr_], BF[fc_], acc[(g) * 4 + fr_][fc_], 0, 0, 0);          \
    __builtin_amdgcn_s_setprio(0);

#define BAR()                                                                 \
    __builtin_amdgcn_sched_barrier(0);                                        \
    __builtin_amdgcn_s_barrier();                                             \
    __builtin_amdgcn_sched_barrier(0);

#define GROUP(c, o, t)                                                        \
  {                                                                           \
    /* stretch 1: stage next A-Kh1, gate on tile t, sync (R13-exact) */       \
    if ((t) + 1 < NT) stageA(o, 1, (t) + 1);                                  \
    if ((t) == NT - 1)                                                        \
        asm volatile("s_waitcnt vmcnt(0)" ::: "memory");                      \
    else                                                                      \
        asm volatile("s_waitcnt vmcnt(6)" ::: "memory");                      \
    BAR();                                                                    \
    /* stretch 2: plane 0; B read once, 2 row-group clusters */               \
    {                                                                         \
        bf16x8 bfr[4];                                                        \
        RD_B(bfr, c, 0);                                                      \
        {                                                                     \
            bf16x8 af[4];                                                     \
            RD_A(af, c, 0, 0);                                                \
            MM16(0, af, bfr);                                                 \
        }                                                                     \
        if ((t) + 1 < NT) stageB(o, 1, (t) + 1);                              \
        {                                                                     \
            bf16x8 af[4];                                                     \
            RD_A(af, c, 1, 0);                                                \
            MM16(1, af, bfr);                                                 \
        }                                                                     \
    }                                                                         \
    BAR();                                                                    \
    /* stretch 3: plane 1; stage Kh0(t+2) into freed planes */                \
    {                                                                         \
        bf16x8 bfr[4];                                                        \
        if ((t) + 2 < NT) stageA(c, 0, (t) + 2);                              \
        RD_B(bfr, c, 1);                                                      \
        {                                                                     \
            bf16x8 af[4];                                                     \
            RD_A(af, c, 0, 1);                                                \
            MM16(0, af, bfr);                                                 \
        }                                                                     \
        if ((t) + 2 < NT) stageB(c, 0, (t) + 2);                              \
        {                                                                     \
            bf16x8 af[4];                                                     \
            RD_A(af, c, 1, 1);                                                \
            MM16(1, af, bfr);                                                 \
        }                                                                     \
    }                                                                         \
    BAR();                                                                    \
  }

template <bool FUSE>
__global__ __launch_bounds__(512) void gemm_bt_bias_relu(
    const unsigned short* __restrict__ A,   // [M,K] bf16 bits
    const unsigned short* __restrict__ BT,  // [N,K] bf16 bits
    const float* __restrict__ bias,         // [N]
    unsigned short* __restrict__ C,         // [M,N] bf16 bits (unused if FUSE)
    const float* __restrict__ W3,           // [N] head weights (FUSE only)
    float* __restrict__ outp,               // [M] (FUSE only)
    int M, int N, int K) {
    // [dbuf][A=0/B=1][plane][row*32 + slot*8 .. ] : 128 KiB total
    __shared__ __align__(16) unsigned short lds[2][2][2][8192];

    const int tid = threadIdx.x;
    const int lane = tid & 63;
    const int wave = tid >> 6;
    const int wm = wave >> 2;   // 0..1 -> rows wm*128..+127
    const int wn = wave & 3;    // 0..3 -> cols wn*64..+63
    const int l15 = lane & 15;
    const int q4 = lane >> 4;   // 0..3

    // ---- m204 bijective XCD chunking over a row-supertile order ----
    const int nRow = M >> 8;            // 127
    const int nCol = N >> 8;            // 8 (GEMM1) / 4 (GEMM2)
    const int nwg = nRow * nCol;
    const int q = nwg >> 3, r = nwg & 7;
    const int x = blockIdx.x & 7;
    const int sidx = blockIdx.x >> 3;
    const int L = (x < r ? x * (q + 1) : r * (q + 1) + (x - r) * q) + sidx;
    const int perSup = 8 * nCol;
    const int nFull = nRow >> 3;        // 15
    const int fullL = nFull * perSup;
    int row_blk, col_blk;
    if (L < fullL) {
        const int sup = L / perSup;
        const int w = L - sup * perSup;
        row_blk = sup * 8 + (w & 7);
        col_blk = w >> 3;
    } else {
        const int rem = L - fullL;
        const int rt = nRow - nFull * 8;  // 7
        row_blk = nFull * 8 + rem % rt;
        col_blk = rem / rt;
    }
    const long row0 = (long)row_blk * 256;
    const long col0 = (long)col_blk * 256;

    // ---- staging source (pre-swizzled global col, rule 21; R13-exact) ----
    const int sg = ((tid & 3) ^ ((tid >> 3) & 3) ^ ((tid >> 5) & 3)) * 8;
    const unsigned short* Ab = A + (row0 + (tid >> 2)) * K + sg;
    const unsigned short* Bb = BT + (col0 + (tid >> 2)) * K + sg;

    auto stageA = [&](int c, int kh, int kt) {
        GLDS16(Ab + (long)kt * 64 + kh * 32, &lds[c][0][kh][tid * 8]);
        GLDS16(Ab + (long)128 * K + (long)kt * 64 + kh * 32,
               &lds[c][0][kh][(512 + tid) * 8]);
    };
    auto stageB = [&](int c, int kh, int kt) {
        GLDS16(Bb + (long)kt * 64 + kh * 32, &lds[c][1][kh][tid * 8]);
        GLDS16(Bb + (long)128 * K + (long)kt * 64 + kh * 32,
               &lds[c][1][kh][(512 + tid) * 8]);
    };

    // ---- per-lane LDS read offsets for 16x16 frags ----
    // frag (i, ks): row = wm*128 + i*16 + l15, k = ks*32 + q4*8 + j
    // plane = ks, chunk = q4, slot = chunk ^ ((row>>1)&3) ^ ((row>>3)&3)
    int baseA16[8], baseB16[4];
    #pragma unroll
    for (int i = 0; i < 8; ++i) {
        int ra = wm * 128 + i * 16 + l15;
        baseA16[i] = ra * 32 + ((q4 ^ ((ra >> 1) & 3) ^ ((ra >> 3) & 3)) * 8);
    }
    #pragma unroll
    for (int fc = 0; fc < 4; ++fc) {
        int rb = wn * 64 + fc * 16 + l15;
        baseB16[fc] = rb * 32 + ((q4 ^ ((rb >> 1) & 3) ^ ((rb >> 3) & 3)) * 8);
    }

    f32x4 acc[8][4];
    #pragma unroll
    for (int i = 0; i < 8; ++i)
        #pragma unroll
        for (int j = 0; j < 4; ++j)
            acc[i][j] = (f32x4)(0.f);

    const int NT = K >> 6;  // K-tiles of 64 (24 / 32 here; even)

    // ---- prologue: tile0 (4 units) + tile1 Kh0 (2 units), 12 loads ----
    stageA(0, 0, 0); stageB(0, 0, 0);
    stageA(0, 1, 0); stageB(0, 1, 0);
    stageA(1, 0, 1); stageB(1, 0, 1);

    for (int t = 0; t < NT; t += 2) {
        GROUP(0, 1, t);
        GROUP(1, 0, t + 1);
    }

    // Epilogue. 16x16 C/D: col=lane&15, row=(lane>>4)*4+reg (m89/m91)
    if (!FUSE) {
        float bv[4];
        #pragma unroll
        for (int fc = 0; fc < 4; ++fc)
            bv[fc] = bias[col0 + wn * 64 + fc * 16 + l15];
        #pragma unroll
        for (int fr = 0; fr < 8; ++fr) {
            #pragma unroll
            for (int reg = 0; reg < 4; ++reg) {
                const long row = row0 + wm * 128 + fr * 16 + q4 * 4 + reg;
                #pragma unroll
                for (int fc = 0; fc < 4; ++fc) {
                    const long col = col0 + wn * 64 + fc * 16 + l15;
                    float v = fmaxf(acc[fr][fc][reg] + bv[fc], 0.f);
                    C[row * N + col] = f2bs(v);
                }
            }
        }
    } else {
        float w3v[4], bv[4];
        #pragma unroll
        for (int fc = 0; fc < 4; ++fc) {
            const long col = col0 + wn * 64 + fc * 16 + l15;
            w3v[fc] = W3[col];
            bv[fc] = bias[col];
        }
        #pragma unroll
        for (int fr = 0; fr < 8; ++fr) {
            #pragma unroll
            for (int reg = 0; reg < 4; ++reg) {
                float s = 0.f;
                #pragma unroll
                for (int fc = 0; fc < 4; ++fc)
                    s += fmaxf(acc[fr][fc][reg] + bv[fc], 0.f) * w3v[fc];
                s += __shfl_xor(s, 1, 64);
                s += __shfl_xor(s, 2, 64);
                s += __shfl_xor(s, 4, 64);
                s += __shfl_xor(s, 8, 64);
                if (l15 == 0) {
                    const long row = row0 + wm * 128 + fr * 16 + q4 * 4 + reg;
                    atomicAdd(&outp[row], s);
                }
            }
        }
    }
}

// ---------------------------------------------------------------------------
// Launch
// ---------------------------------------------------------------------------
extern "C" void kernel_launch(void* const* d_in, const int* in_sizes, int n_in,
                              void* d_out, int out_size, void* d_ws,
                              size_t ws_size, hipStream_t stream) {
    const float* h  = (const float*)d_in[0];
    const float* W1 = (const float*)d_in[1];
    const float* b1 = (const float*)d_in[2];
    const float* W2 = (const float*)d_in[3];
    const float* b2 = (const float*)d_in[4];
    const float* W3 = (const float*)d_in[5];
    const float* b3 = (const float*)d_in[6];
    float* out = (float*)d_out;

    const int B = 128, T = 254, D = 768, H = 1024;
    const int M = B * T;        // 32512 = 127 * 256
    const int K1 = 2 * D;       // 1536
    const int N1 = 2 * H;       // 2048
    const int K2 = N1;          // 2048
    const int N2 = H;           // 1024
    const int nC = (T + TCHUNK - 1) / TCHUNK;  // 16

    char* ws = (char*)d_ws;
    size_t off = 0;
    auto alloc = [&](size_t bytes) {
        char* p = ws + off;
        off += (bytes + 255) & ~(size_t)255;
        return p;
    };
    unsigned short* X   = (unsigned short*)alloc((size_t)M * K1 * 2);  // 99.9 MB
    unsigned short* H1  = (unsigned short*)alloc((size_t)M * N1 * 2);  // 133.2 MB
    unsigned short* W1T = (unsigned short*)alloc((size_t)N1 * K1 * 2); // 6.3 MB
    unsigned short* W2T = (unsigned short*)alloc((size_t)N2 * K2 * 2); // 4.2 MB
    float* partial      = (float*)alloc((size_t)B * nC * D * 4);       // 6.3 MB

    dim3 tb(32, 8);
    transpose_cast<<<dim3(N1 / 32, K1 / 32), tb, 0, stream>>>(W1, W1T, K1, N1);
    transpose_cast<<<dim3(N2 / 32, K2 / 32), tb, 0, stream>>>(W2, W2T, K2, N2);

    // TCHUNK=16: 2048 blocks = 8/CU = 24 waves/CU (was 12)
    feats_partial<<<dim3(B, nC), 192, 0, stream>>>(h, partial, X, B, T, D, nC);
    feats_write<<<dim3(B, nC), 192, 0, stream>>>(h, partial, X, B, T, D, nC);

    init_out<<<dim3((M + 255) / 256), 256, 0, stream>>>(out, b3, M);

    // 256x256 tiles, 512 threads, R17 16x16x32 core (frozen)
    gemm_bt_bias_relu<false><<<dim3((M / 256) * (N1 / 256)), 512, 0, stream>>>(
        X, W1T, b1, H1, nullptr, nullptr, M, N1, K1);
    gemm_bt_bias_relu<true><<<dim3((M / 256) * (N2 / 256)), 512, 0, stream>>>(
        H1, W2T, b2, nullptr, W3, out, M, N2, K2);
}